// Round 4
// baseline (1195.471 us; speedup 1.0000x reference)
//
#include <hip/hip_runtime.h>
#include <math.h>

// Problem constants
#define NB 128
#define NI 2048
#define NU 16
#define NJ 32
#define NV 16
#define NJV 512

// Tiling
#define BI 16          // i's per block
#define IC (NI / BI)   // 128
#define BB 32          // b's per block
#define GB (NB / BB)   // 4
#define WB 8           // b's per wave

#define GLD16(g, l) __builtin_amdgcn_global_load_lds( \
    (const __attribute__((address_space(1))) unsigned int*)(g), \
    (__attribute__((address_space(3))) unsigned int*)(l), 16, 0, 0)

// 16-lane butterfly reduce, pure-VALU via DPP (no LDS pipe!)
template<int CTRL>
__device__ __forceinline__ float dpp_add(float x) {
    int t = __builtin_amdgcn_update_dpp(0, __float_as_int(x), CTRL, 0xf, 0xf, true);
    return x + __int_as_float(t);
}
__device__ __forceinline__ float red16(float x) {
    x = dpp_add<0xB1>(x);    // quad_perm [1,0,3,2]  (xor 1)
    x = dpp_add<0x4E>(x);    // quad_perm [2,3,0,1]  (xor 2)
    x = dpp_add<0x141>(x);   // row_half_mirror      (xor 7)
    x = dpp_add<0x140>(x);   // row_mirror           (xor 15)
    return x;
}

// Lane L owns jv slots {L + 64k : k=0..7}; j = 4k + (L>>4), v = L&15.
// W[i] staged into LDS with a PERMUTED layout so that each ds_read_b128 is
// 64 lanes x contiguous 16B (conflict-free): slot((k',q),L) = (k'*4+q)*64 + L.
// Inverse permutation is applied on the global SOURCE address of
// global_load_lds (LDS dest stays linear: wave-uniform base + lane*16).
template<int MODE>
__global__ __launch_bounds__(256, 2)
void pass_kernel(const float* __restrict__ x, const float* __restrict__ W,
                 const float* __restrict__ Vacc, float* __restrict__ s_out)
{
    __shared__ float Wlds[2][4096];       // 2 x 16 KB: buf0 = k 0..3, buf1 = k 4..7

    const int tid  = threadIdx.x;
    const int lane = tid & 63;
    const int wave = tid >> 6;
    const int ibase = blockIdx.x * BI;
    const int b0    = blockIdx.y * BB + wave * WB;

    // staging source sub-offset (bytes), thread-constant:
    // thread t stages element (j=16H+4p+g, v, u-quad q) with g=(t>>4)&3, v=t&15, q=t>>6
    const int soff = ((tid >> 4) & 3) * 1024 + (tid & 15) * 64 + (tid >> 6) * 16;
    const char* Wb = (const char*)W;

#define STAGE(i_, Hh, buf_)                                                     \
    {                                                                           \
        const char* srcp = Wb + (size_t)(i_) * 32768 + (Hh) * 16384 + soff;     \
        _Pragma("unroll")                                                       \
        for (int p = 0; p < 4; ++p)                                             \
            GLD16(srcp + p * 4096, &Wlds[buf_][(p * 256 + tid) * 4]);           \
    }

    float vacc[WB][8];
    if (MODE) {
#pragma unroll
        for (int b = 0; b < WB; ++b)
#pragma unroll
            for (int k = 0; k < 8; ++k)
                vacc[b][k] = Vacc[(size_t)(b0 + b) * NJV + lane + 64 * k];
    }

    float s_local[WB][8];
#pragma unroll
    for (int b = 0; b < WB; ++b)
#pragma unroll
        for (int k = 0; k < 8; ++k) s_local[b][k] = 0.f;
    float uv[WB][8];   // MODE1 only (dead in MODE0)

#define COMPUTE_HALF(Hh)                                                        \
    {                                                                           \
        _Pragma("unroll")                                                       \
        for (int q = 0; q < 4; ++q) {                                           \
            float4 xv[WB];                                                      \
            _Pragma("unroll")                                                   \
            for (int b = 0; b < WB; ++b)                                        \
                xv[b] = *(const float4*)(x + ((size_t)(b0 + b) * NI + i) * NU + q * 4); \
            _Pragma("unroll")                                                   \
            for (int kp = 0; kp < 4; ++kp) {                                    \
                float4 w = *(const float4*)&Wlds[Hh][kp * 1024 + q * 256 + lane * 4]; \
                _Pragma("unroll")                                               \
                for (int b = 0; b < WB; ++b) {                                  \
                    if (MODE) {                                                 \
                        float a = (q == 0) ? xv[b].x * w.x                      \
                                           : fmaf(xv[b].x, w.x, uv[b][(Hh)*4+kp]); \
                        a = fmaf(xv[b].y, w.y, a);                              \
                        a = fmaf(xv[b].z, w.z, a);                              \
                        a = fmaf(xv[b].w, w.w, a);                              \
                        uv[b][(Hh)*4+kp] = a;                                   \
                    } else {                                                    \
                        float a = fmaf(xv[b].x, w.x, s_local[b][(Hh)*4+kp]);    \
                        a = fmaf(xv[b].y, w.y, a);                              \
                        a = fmaf(xv[b].z, w.z, a);                              \
                        a = fmaf(xv[b].w, w.w, a);                              \
                        s_local[b][(Hh)*4+kp] = a;                              \
                    }                                                           \
                }                                                               \
            }                                                                   \
        }                                                                       \
    }

    // prologue: stage (i0, lo)
    STAGE(ibase, 0, 0);

    for (int il = 0; il < BI; ++il) {
        const int i = ibase + il;

        // A: stage hi of this i, wait for lo (counted: keep hi in flight)
        STAGE(i, 1, 1);
        asm volatile("s_waitcnt vmcnt(4)" ::: "memory");
        __builtin_amdgcn_s_barrier();
        asm volatile("" ::: "memory");

        COMPUTE_HALF(0);

        asm volatile("" ::: "memory");
        __builtin_amdgcn_s_barrier();      // all waves done reading buf0
        if (il < BI - 1) {
            STAGE(i + 1, 0, 0);
            asm volatile("s_waitcnt vmcnt(4)" ::: "memory");   // hi done, lo' flying
        } else {
            asm volatile("s_waitcnt vmcnt(0)" ::: "memory");
        }
        __builtin_amdgcn_s_barrier();
        asm volatile("" ::: "memory");

        COMPUTE_HALF(1);

        if (MODE) {
            // routing: logits -> softmax -> weighted accumulate (register-only + 2 LDS-pipe ops/b)
#pragma unroll
            for (int b = 0; b < WB; ++b) {
                float p8[8];
#pragma unroll
                for (int k = 0; k < 8; ++k) p8[k] = uv[b][k] * vacc[b][k];
#pragma unroll
                for (int k = 0; k < 8; ++k) p8[k] = red16(p8[k]);   // dot over v (16 lanes)
                float e8[8], sl = 0.f;
#pragma unroll
                for (int k = 0; k < 8; ++k) { e8[k] = __expf(p8[k]); sl += e8[k]; }
                // combine the 4 lane-groups: xor16 (ds_swizzle) + xor32 (ds_bpermute)
                sl += __int_as_float(__builtin_amdgcn_ds_swizzle(__float_as_int(sl), 0x401F));
                sl += __int_as_float(__builtin_amdgcn_ds_bpermute((lane ^ 32) << 2,
                                                                  __float_as_int(sl)));
                float inv = __builtin_amdgcn_rcpf(sl);
#pragma unroll
                for (int k = 0; k < 8; ++k)
                    s_local[b][k] = fmaf(e8[k] * inv, uv[b][k], s_local[b][k]);
            }
        }

        asm volatile("" ::: "memory");
        __builtin_amdgcn_s_barrier();      // all waves done reading buf1
        asm volatile("" ::: "memory");
    }

    // epilogue: one atomicAdd per (b, slot)
    const float scale = (MODE == 0) ? (1.0f / NJ) : 1.0f;
#pragma unroll
    for (int b = 0; b < WB; ++b)
#pragma unroll
        for (int k = 0; k < 8; ++k)
            atomicAdd(&s_out[(size_t)(b0 + b) * NJV + lane + 64 * k],
                      s_local[b][k] * scale);
#undef STAGE
#undef COMPUTE_HALF
}

// squash + bias; mode 0: Vacc = v ; mode 1: Vacc += v ; mode 2: out = v
__global__ __launch_bounds__(256)
void squash_kernel(const float* __restrict__ s_in, const float* __restrict__ bias,
                   float* __restrict__ Vacc, float* __restrict__ out, int mode)
{
    int idx = blockIdx.x * 256 + threadIdx.x;    // over NB*NJV = 65536
    float s = s_in[idx] + bias[idx & (NJV - 1)];
    float sq = s * s;
#pragma unroll
    for (int m = 1; m < 16; m <<= 1) sq += __shfl_xor(sq, m, 64);
    float val = s * sq / (1.0f + sq) / sqrtf(sq + 1e-9f);
    if (mode == 0)      Vacc[idx] = val;
    else if (mode == 1) Vacc[idx] += val;
    else                out[idx]  = val;
}

extern "C" void kernel_launch(void* const* d_in, const int* in_sizes, int n_in,
                              void* d_out, int out_size, void* d_ws, size_t ws_size,
                              hipStream_t stream)
{
    const float* x    = (const float*)d_in[0];
    const float* W    = (const float*)d_in[1];
    const float* bias = (const float*)d_in[2];
    float* out = (float*)d_out;

    float* s_buf = (float*)d_ws;             // NB*NJV floats = 256 KB
    float* Vacc  = s_buf + NB * NJV;         // NB*NJV floats = 256 KB

    dim3 grid(IC, GB), blk(256);
    dim3 sgrid(NB * NJV / 256), sblk(256);
    size_t s_bytes = (size_t)NB * NJV * sizeof(float);

    // r = 0: uniform coupling (softmax of zeros)
    (void)hipMemsetAsync(s_buf, 0, s_bytes, stream);
    pass_kernel<0><<<grid, blk, 0, stream>>>(x, W, Vacc, s_buf);
    squash_kernel<<<sgrid, sblk, 0, stream>>>(s_buf, bias, Vacc, out, 0); // Vacc = v0

    // r = 1: logits = u . v0
    (void)hipMemsetAsync(s_buf, 0, s_bytes, stream);
    pass_kernel<1><<<grid, blk, 0, stream>>>(x, W, Vacc, s_buf);
    squash_kernel<<<sgrid, sblk, 0, stream>>>(s_buf, bias, Vacc, out, 1); // Vacc += v1

    // r = 2: logits = u . (v0+v1)
    (void)hipMemsetAsync(s_buf, 0, s_bytes, stream);
    pass_kernel<1><<<grid, blk, 0, stream>>>(x, W, Vacc, s_buf);
    squash_kernel<<<sgrid, sblk, 0, stream>>>(s_buf, bias, Vacc, out, 2); // out = v2
}

// Round 5
// 584.396 us; speedup vs baseline: 2.0456x; 2.0456x over previous
//
#include <hip/hip_runtime.h>
#include <math.h>

// Problem constants
#define NB 128
#define NI 2048
#define NU 16
#define NJ 32
#define NV 16
#define NJV 512

// Tiling
#define BI 16          // i's per block
#define IC (NI / BI)   // 128
#define BB 32          // b's per block
#define GB (NB / BB)   // 4
#define WB 8           // b's per wave

#define GLD16(g, l) __builtin_amdgcn_global_load_lds( \
    (const __attribute__((address_space(1))) unsigned int*)(g), \
    (__attribute__((address_space(3))) unsigned int*)(l), 16, 0, 0)

// 16-lane butterfly reduce, pure-VALU via DPP (no LDS pipe)
template<int CTRL>
__device__ __forceinline__ float dpp_add(float x) {
    int t = __builtin_amdgcn_update_dpp(0, __float_as_int(x), CTRL, 0xf, 0xf, true);
    return x + __int_as_float(t);
}
__device__ __forceinline__ float red16(float x) {
    x = dpp_add<0xB1>(x);    // quad_perm [1,0,3,2]  (xor 1)
    x = dpp_add<0x4E>(x);    // quad_perm [2,3,0,1]  (xor 2)
    x = dpp_add<0x141>(x);   // row_half_mirror      (xor 7)
    x = dpp_add<0x140>(x);   // row_mirror           (xor 15)
    return x;
}

// Lane L owns jv slots {L + 64k : k=0..7}; j = 4k + (L>>4), v = L&15.
// W[i] (32 KB) staged into LDS with a PERMUTED layout so each ds_read_b128 is
// 64 lanes x contiguous 16B (conflict-free): float_off(k,q,L) = (k*4+q)*256 + L*4
// holds W[i][4k+(L>>4)][L&15][4q..4q+3]. The inverse permutation is applied on
// the global SOURCE address of global_load_lds; the LDS dest stays linear.
template<int MODE>
__global__ __launch_bounds__(256, 1)
void pass_kernel(const float* __restrict__ x, const float* __restrict__ W,
                 const float* __restrict__ Vacc, float* __restrict__ s_out)
{
    __shared__ float Wlds[2][8192];       // 2 x 32 KB double buffer

    const int tid  = threadIdx.x;
    const int lane = tid & 63;
    const int wave = tid >> 6;
    const int ibase = blockIdx.x * BI;
    const int b0    = blockIdx.y * BB + wave * WB;

    // staging source sub-offset (bytes): thread t, inst p stages fragment
    // (k=p, q=t>>6, L=t&63) -> global byte off = p*4096 + soff
    const int soff = ((tid >> 4) & 3) * 1024 + (tid & 15) * 64 + (tid >> 6) * 16;
    const char* Wb = (const char*)W;

#define STAGE(i_, buf_)                                                         \
    {                                                                           \
        const char* srcp = Wb + (size_t)(i_) * 32768 + soff;                    \
        _Pragma("unroll")                                                       \
        for (int p = 0; p < 8; ++p)                                             \
            GLD16(srcp + p * 4096, &Wlds[buf_][p * 1024 + tid * 4]);            \
    }

    float vacc[WB][8];
    if (MODE) {
#pragma unroll
        for (int b = 0; b < WB; ++b)
#pragma unroll
            for (int k = 0; k < 8; ++k)
                vacc[b][k] = Vacc[(size_t)(b0 + b) * NJV + lane + 64 * k];
    }

    float s_local[WB][8];
#pragma unroll
    for (int b = 0; b < WB; ++b)
#pragma unroll
        for (int k = 0; k < 8; ++k) s_local[b][k] = 0.f;
    float uv[WB][8];   // MODE1 only (dead in MODE0)

    // prologue
    STAGE(ibase, 0);

    for (int il = 0; il < BI; ++il) {
        const int i   = ibase + il;
        const int cur = il & 1;

        if (il < BI - 1) {
            STAGE(i + 1, cur ^ 1);
            asm volatile("s_waitcnt vmcnt(8)" ::: "memory");  // cur buf done, next in flight
        } else {
            asm volatile("s_waitcnt vmcnt(0)" ::: "memory");
        }
        __builtin_amdgcn_s_barrier();
        asm volatile("" ::: "memory");

        // compute votes for this i (8 b's per wave)
#pragma unroll
        for (int q = 0; q < 4; ++q) {
            float4 xv[WB];
#pragma unroll
            for (int b = 0; b < WB; ++b)
                xv[b] = *(const float4*)(x + ((size_t)(b0 + b) * NI + i) * NU + q * 4);
#pragma unroll
            for (int k = 0; k < 8; ++k) {
                float4 w = *(const float4*)&Wlds[cur][(k * 4 + q) * 256 + lane * 4];
#pragma unroll
                for (int b = 0; b < WB; ++b) {
                    if (MODE) {
                        float a = (q == 0) ? xv[b].x * w.x
                                           : fmaf(xv[b].x, w.x, uv[b][k]);
                        a = fmaf(xv[b].y, w.y, a);
                        a = fmaf(xv[b].z, w.z, a);
                        a = fmaf(xv[b].w, w.w, a);
                        uv[b][k] = a;
                    } else {
                        float a = fmaf(xv[b].x, w.x, s_local[b][k]);
                        a = fmaf(xv[b].y, w.y, a);
                        a = fmaf(xv[b].z, w.z, a);
                        a = fmaf(xv[b].w, w.w, a);
                        s_local[b][k] = a;
                    }
                }
            }
        }

        if (MODE) {
            // routing: logits -> softmax -> weighted accumulate
#pragma unroll
            for (int b = 0; b < WB; ++b) {
                float p8[8];
#pragma unroll
                for (int k = 0; k < 8; ++k) p8[k] = uv[b][k] * vacc[b][k];
#pragma unroll
                for (int k = 0; k < 8; ++k) p8[k] = red16(p8[k]);   // dot over v
                float sl = 0.f;
#pragma unroll
                for (int k = 0; k < 8; ++k) { p8[k] = __expf(p8[k]); sl += p8[k]; }
                // combine the 4 lane-groups: xor16 (ds_swizzle) + xor32 (ds_bpermute)
                sl += __int_as_float(__builtin_amdgcn_ds_swizzle(__float_as_int(sl), 0x401F));
                sl += __int_as_float(__builtin_amdgcn_ds_bpermute((lane ^ 32) << 2,
                                                                  __float_as_int(sl)));
                float inv = __builtin_amdgcn_rcpf(sl);
#pragma unroll
                for (int k = 0; k < 8; ++k)
                    s_local[b][k] = fmaf(p8[k] * inv, uv[b][k], s_local[b][k]);
            }
        }

        asm volatile("" ::: "memory");
        __builtin_amdgcn_s_barrier();      // all waves done reading cur buf
        asm volatile("" ::: "memory");
    }

    // epilogue: one atomicAdd per (b, slot)
    const float scale = (MODE == 0) ? (1.0f / NJ) : 1.0f;
#pragma unroll
    for (int b = 0; b < WB; ++b)
#pragma unroll
        for (int k = 0; k < 8; ++k)
            atomicAdd(&s_out[(size_t)(b0 + b) * NJV + lane + 64 * k],
                      s_local[b][k] * scale);
#undef STAGE
}

// squash + bias; mode 0: Vacc = v ; mode 1: Vacc += v ; mode 2: out = v
__global__ __launch_bounds__(256)
void squash_kernel(const float* __restrict__ s_in, const float* __restrict__ bias,
                   float* __restrict__ Vacc, float* __restrict__ out, int mode)
{
    int idx = blockIdx.x * 256 + threadIdx.x;    // over NB*NJV = 65536
    float s = s_in[idx] + bias[idx & (NJV - 1)];
    float sq = s * s;
#pragma unroll
    for (int m = 1; m < 16; m <<= 1) sq += __shfl_xor(sq, m, 64);
    float val = s * sq / (1.0f + sq) / sqrtf(sq + 1e-9f);
    if (mode == 0)      Vacc[idx] = val;
    else if (mode == 1) Vacc[idx] += val;
    else                out[idx]  = val;
}

extern "C" void kernel_launch(void* const* d_in, const int* in_sizes, int n_in,
                              void* d_out, int out_size, void* d_ws, size_t ws_size,
                              hipStream_t stream)
{
    const float* x    = (const float*)d_in[0];
    const float* W    = (const float*)d_in[1];
    const float* bias = (const float*)d_in[2];
    float* out = (float*)d_out;

    float* s_buf = (float*)d_ws;             // NB*NJV floats = 256 KB
    float* Vacc  = s_buf + NB * NJV;         // NB*NJV floats = 256 KB

    dim3 grid(IC, GB), blk(256);
    dim3 sgrid(NB * NJV / 256), sblk(256);
    size_t s_bytes = (size_t)NB * NJV * sizeof(float);

    // r = 0: uniform coupling (softmax of zeros)
    (void)hipMemsetAsync(s_buf, 0, s_bytes, stream);
    pass_kernel<0><<<grid, blk, 0, stream>>>(x, W, Vacc, s_buf);
    squash_kernel<<<sgrid, sblk, 0, stream>>>(s_buf, bias, Vacc, out, 0); // Vacc = v0

    // r = 1: logits = u . v0
    (void)hipMemsetAsync(s_buf, 0, s_bytes, stream);
    pass_kernel<1><<<grid, blk, 0, stream>>>(x, W, Vacc, s_buf);
    squash_kernel<<<sgrid, sblk, 0, stream>>>(s_buf, bias, Vacc, out, 1); // Vacc += v1

    // r = 2: logits = u . (v0+v1)
    (void)hipMemsetAsync(s_buf, 0, s_bytes, stream);
    pass_kernel<1><<<grid, blk, 0, stream>>>(x, W, Vacc, s_buf);
    squash_kernel<<<sgrid, sblk, 0, stream>>>(s_buf, bias, Vacc, out, 2); // out = v2
}